// Round 10
// baseline (311.250 us; speedup 1.0000x reference)
//
#include <hip/hip_runtime.h>

typedef __attribute__((ext_vector_type(4))) float f32x4;

#define T_STEPS 32
#define NROWS 4096
#define DR2 512
#define EXP_HALF 0.6065306597126334f

#define OUT_HFINAL 67108864ul           /* 32*4096*512              */
#define OUT_DIFF   69206016ul           /* + 4096*512               */
#define SLOT_F32   2097152ul            /* 4096*512 f32 per t-slot  */

__device__ __forceinline__ unsigned char f2fp8(float f) {
  return (unsigned char)__builtin_amdgcn_cvt_pk_fp8_f32(f, f, 0, false);
}
__device__ __forceinline__ unsigned int pack4fp8(float a, float b, float c, float d) {
  int p = __builtin_amdgcn_cvt_pk_fp8_f32(a, b, 0, false);
  p = __builtin_amdgcn_cvt_pk_fp8_f32(c, d, p, true);
  return (unsigned int)p;
}

// LDS-only barrier: skips the vmcnt(0) drain __syncthreads would emit.
// Safe: all cross-wave hazards at these barriers are LDS; aliased global
// reads are register-consumed (vmcnt-waited) before the barrier that
// precedes the aliasing write.
__device__ __forceinline__ void barrier_lds() {
  asm volatile("s_waitcnt lgkmcnt(0)" ::: "memory");
  __builtin_amdgcn_s_barrier();
  asm volatile("" ::: "memory");
}

// z_s[t] stored as fp8 e4m3 RESIDUAL r = z_s - 256 (z_s ~ 256 +/- 40),
// aliased into d_out (diff slot t for t<31, hfinal for t=31), block-self-
// owned: read at step t, overwritten by the same block's diff[t+1] at step
// t+2, with two barriers in between.
__device__ __forceinline__ float* zs_slot(float* out, int t) {
  return out + (t < 31 ? OUT_DIFF + (size_t)t * SLOT_F32 : OUT_HFINAL);
}
__device__ __forceinline__ unsigned char* zs_blk8(float* out, int t, int eb) {
  return (unsigned char*)zs_slot(out, t) + (size_t)eb * 32768;
}

// ---- swapped-operand design ----
// MFMA computes z^T: A = W1 fragments (w1f, unchanged bytes), B = h/s tile.
// Verified layouts (same as rounds 4-9, roles swapped):
//   A: lane l holds W1[k = 32kk + (l>>4)*8 + e][m = l&15]   (z-col m)
//   B: lane l holds X [row n = l&15][k = 32kk + (l>>4)*8 + e]
//   C/D: thread (l15,lg) holds z[row l15][col 16*mt + 4*lg + i], i=0..3
// B-tile LDS layout [16 rows][512 k] fp8 with XOR swizzle:
//   byte(row, k) = row*512 + ((k>>3) ^ row)*8 + (k&7)
// read (l15 varies per lane, k8 fixed): banks 2*((k8^l15)&15) distinct ->
// conflict-free; write per thread is one aligned b32/b64.

// ---------- prologue: w1 [1024][512] f32 -> w1f fragment-ordered fp8
__global__ __launch_bounds__(256) void quant_w1(const float* __restrict__ w1,
                                                unsigned char* __restrict__ w1f) {
  const int half = blockIdx.x >> 5;       // 0..1
  const int ct   = blockIdx.x & 31;       // 0..31
  const int l15  = threadIdx.x & 15;
  const int kk   = threadIdx.x >> 4;      // 0..15
  const int col  = ct * 16 + l15;
  const int K0   = half * 512;
#pragma unroll
  for (int lg = 0; lg < 4; lg++) {
    unsigned long long v = 0;
#pragma unroll
    for (int e = 0; e < 8; e++) {
      int k = K0 + kk * 32 + lg * 8 + e;
      unsigned long long b = f2fp8(w1[(size_t)k * 512 + col]);
      v |= b << (8 * e);
    }
    *(unsigned long long*)(w1f + (size_t)half * 262144 + ct * 8192 + kk * 512
                           + lg * 128 + l15 * 8) = v;
  }
}

// ---------- phase 1: dense z_s[t]^T tiles = W1s^T x s_t^T (fp8 MFMA)
__global__ __attribute__((amdgpu_flat_work_group_size(1024, 1024),
                          amdgpu_waves_per_eu(4, 4)))
void dense_zs(
    const float* __restrict__ s_all,        // [32][4096][512] f32
    const unsigned char* __restrict__ w1f,  // fragment-ordered fp8
    float* __restrict__ out)
{
  __shared__ __align__(16) unsigned char A_lds[2][8192];
  const int tid  = threadIdx.x;
  const int lane = tid & 63;
  const int wave = tid >> 6;              // 0..15
  const int l15  = lane & 15;
  const int lg   = lane >> 4;
  const int t    = blockIdx.x >> 5;
  const int rc   = blockIdx.x & 31;

  // A = W1s (half=1) fragments, register-resident
  long Av[2][16];
#pragma unroll
  for (int mt = 0; mt < 2; mt++)
#pragma unroll
    for (int kk = 0; kk < 16; kk++)
      Av[mt][kk] = *(const long*)(w1f + 262144
                    + (size_t)(wave * 2 + mt) * 8192 + kk * 512 + lane * 8);

  // staging: wave stages row=wave, lane covers k = lane*8..+7 (one b64 slot)
  const int di = wave * 512 + ((lane ^ wave) << 3);  // XOR-swizzled slot
  const float* srow = s_all + ((size_t)t * NROWS + rc * 128 + wave) * DR2 + lane * 8;

  float4 v0 = *(const float4*)srow;
  float4 v1 = *(const float4*)(srow + 4);
  {
    int pa = __builtin_amdgcn_cvt_pk_fp8_f32(v0.x, v0.y, 0, false);
    int pw0 = __builtin_amdgcn_cvt_pk_fp8_f32(v0.z, v0.w, pa, true);
    int pb = __builtin_amdgcn_cvt_pk_fp8_f32(v1.x, v1.y, 0, false);
    int pw1 = __builtin_amdgcn_cvt_pk_fp8_f32(v1.z, v1.w, pb, true);
    *(uint2*)(A_lds[0] + di) = make_uint2((unsigned)pw0, (unsigned)pw1);
  }
  barrier_lds();

#pragma unroll
  for (int j = 0; j < 8; j++) {
    if (j < 7) {
      const float* p = srow + (size_t)(j + 1) * 16 * DR2;
      v0 = *(const float4*)p;
      v1 = *(const float4*)(p + 4);
    }
    // acc init -256 -> D = z_s - 256 = residual directly
    f32x4 acc[2];
#pragma unroll
    for (int mt = 0; mt < 2; mt++)
#pragma unroll
      for (int i = 0; i < 4; i++) acc[mt][i] = -256.0f;
    const unsigned char* buf = A_lds[j & 1];
#pragma unroll
    for (int kk = 0; kk < 16; kk++) {
      long b = *(const long*)(buf + l15 * 512 + (((kk << 2) | lg) ^ l15) * 8);
      acc[0] = __builtin_amdgcn_mfma_f32_16x16x32_fp8_fp8(Av[0][kk], b, acc[0], 0, 0, 0);
      acc[1] = __builtin_amdgcn_mfma_f32_16x16x32_fp8_fp8(Av[1][kk], b, acc[1], 0, 0, 0);
    }
    // thread holds z_s[row l15][16mt + 4lg + i] - 256; pack 8 fp8, store 8B
    unsigned int p0 = pack4fp8(acc[0][0], acc[0][1], acc[0][2], acc[0][3]);
    unsigned int p1 = pack4fp8(acc[1][0], acc[1][1], acc[1][2], acc[1][3]);
    *(uint2*)(zs_blk8(out, t, rc * 8 + j) + (size_t)tid * 8) = make_uint2(p0, p1);

    if (j < 7) {
      int pa = __builtin_amdgcn_cvt_pk_fp8_f32(v0.x, v0.y, 0, false);
      int pw0 = __builtin_amdgcn_cvt_pk_fp8_f32(v0.z, v0.w, pa, true);
      int pb = __builtin_amdgcn_cvt_pk_fp8_f32(v1.x, v1.y, 0, false);
      int pw1 = __builtin_amdgcn_cvt_pk_fp8_f32(v1.z, v1.w, pb, true);
      *(uint2*)(A_lds[(j + 1) & 1] + di) = make_uint2((unsigned)pw0, (unsigned)pw1);
      barrier_lds();
    }
  }
}

// ---------- phase 2: recurrent. 256 blocks x 1024 threads, 16 rows/block.
__global__ __attribute__((amdgpu_flat_work_group_size(1024, 1024),
                          amdgpu_waves_per_eu(4, 4)))
void evolve_fp8(
    const float* __restrict__ thr_all,      // [32][4096]
    const float* __restrict__ h0,           // [4096][512]
    const unsigned char* __restrict__ w1f,  // fragment-ordered fp8
    const float* __restrict__ p_logit,
    const float* __restrict__ p_scale,
    float* __restrict__ out)
{
  __shared__ __align__(16) unsigned char H_lds[8192];  // [16 rows][512 k] fp8
  __shared__ float thr_lds[T_STEPS * 16];              // 2 KB, preloaded once
  __shared__ float partial[16][17];

  const int tid  = threadIdx.x;
  const int lane = tid & 63;
  const int wave = tid >> 6;
  const int l15  = lane & 15;               // = this thread's row
  const int lg   = lane >> 4;
  const int brow0 = blockIdx.x * 16;
  const int colb  = wave * 32 + lg * 4;     // + 16*mt

  const float glogit = *p_logit;
  const float gscale = *p_scale;

  // A = W1h (half=0) fragments, register-resident (64 VGPR)
  long Av[2][16];
#pragma unroll
  for (int mt = 0; mt < 2; mt++)
#pragma unroll
    for (int kk = 0; kk < 16; kk++)
      Av[mt][kk] = *(const long*)(w1f + (size_t)(wave * 2 + mt) * 8192
                                  + kk * 512 + lane * 8);

  // h state: thread holds row l15, cols colb+16mt .. +3 (float4-contiguous)
  f32x4 h[2];
  {
    const float* hrow = h0 + (size_t)(brow0 + l15) * DR2 + colb;
    h[0] = *(const f32x4*)hrow;
    h[1] = *(const f32x4*)(hrow + 16);
  }

  if (tid < T_STEPS * 16)
    thr_lds[tid] = thr_all[(size_t)(tid >> 4) * NROWS + brow0 + (tid & 15)];

  // z_s residual for current step, loaded one step ahead
  uint2 zraw = *(const uint2*)(zs_blk8(out, 0, blockIdx.x) + (size_t)tid * 8);

#pragma unroll 1
  for (int t = 0; t < T_STEPS; t++) {
    // ---- stage h (fp8) into H_lds: 2 aligned b32 writes per thread
#pragma unroll
    for (int mt = 0; mt < 2; mt++) {
      int c = colb + mt * 16;
      int addr = l15 * 512 + (((c >> 3) ^ l15) << 3) + (c & 7);
      *(unsigned int*)(H_lds + addr) = pack4fp8(h[mt][0], h[mt][1], h[mt][2], h[mt][3]);
    }
    uint2 znext;
    if (t + 1 < T_STEPS)
      znext = *(const uint2*)(zs_blk8(out, t + 1, blockIdx.x) + (size_t)tid * 8);
    barrier_lds();                        // B1 (LDS-only)

    // ---- GEMM: z^T = W1h^T x h^T ; acc init 256 un-biases the residual
    f32x4 acc[2];
#pragma unroll
    for (int mt = 0; mt < 2; mt++)
#pragma unroll
      for (int i = 0; i < 4; i++) acc[mt][i] = 256.0f;
#pragma unroll
    for (int kk = 0; kk < 16; kk++) {
      long b = *(const long*)(H_lds + l15 * 512 + (((kk << 2) | lg) ^ l15) * 8);
      acc[0] = __builtin_amdgcn_mfma_f32_16x16x32_fp8_fp8(Av[0][kk], b, acc[0], 0, 0, 0);
      acc[1] = __builtin_amdgcn_mfma_f32_16x16x32_fp8_fp8(Av[1][kk], b, acc[1], 0, 0, 0);
    }
    // ---- z += residual (e4m3 decode via exponent re-bias)
    {
      const unsigned int zw[2] = { zraw.x, zraw.y };
#pragma unroll
      for (int j = 0; j < 8; j++) {
        unsigned int b = (zw[j >> 2] >> ((j & 3) * 8)) & 0xffu;
        unsigned int man = (b & 0x7fu) << 20;
        unsigned int bits = ((b & 0x80u) << 24) | (man + (120u << 23));
        acc[j >> 2][j & 3] += __uint_as_float(bits);
      }
    }

    // ---- epilogue: cand; row-sum is 7 LOCAL adds + 2 shfl (row = l15)
    const float th = thr_lds[t * 16 + l15];
    f32x4 cand[2];
    float s = 0.f;
#pragma unroll
    for (int mt = 0; mt < 2; mt++)
#pragma unroll
      for (int i = 0; i < 4; i++) {
        float hh = h[mt][i];
        float x  = acc[mt][i] * th + hh * (1.0f - th);
        float c  = EXP_HALF / (1.0f + __expf(-x));
        cand[mt][i] = c;
        s += fabsf(c - hh);
      }
    s += __shfl_xor(s, 16);
    s += __shfl_xor(s, 32);               // sum over this wave's 32 cols
    if (lane < 16) partial[l15][wave] = s;
    barrier_lds();                        // B2 (LDS-only)

    // ---- gate for row l15 (this thread's own row -- no bpermute needed)
    float tot = partial[l15][lg] + partial[l15][lg + 4]
              + partial[l15][lg + 8] + partial[l15][lg + 12];
    tot += __shfl_xor(tot, 16);
    tot += __shfl_xor(tot, 32);
    float g = 1.0f / (1.0f + __expf(-(glogit + gscale * (tot * (1.0f / 512.0f)))));

    // ---- gated update; float4 stores for states[t] and diff[t-1]
    const size_t sbase = ((size_t)t * NROWS + brow0 + l15) * DR2 + colb;
    f32x4 hn[2], df[2];
#pragma unroll
    for (int mt = 0; mt < 2; mt++)
#pragma unroll
      for (int i = 0; i < 4; i++) {
        float hh = h[mt][i];
        float v  = g * hh + (1.0f - g) * cand[mt][i];
        hn[mt][i] = v;
        df[mt][i] = v - hh;
        h[mt][i]  = v;
      }
    *(f32x4*)(out + sbase)      = hn[0];
    *(f32x4*)(out + sbase + 16) = hn[1];
    if (t > 0) {
      const size_t dbase = OUT_DIFF + sbase - (size_t)NROWS * DR2;
      *(f32x4*)(out + dbase)      = df[0];
      *(f32x4*)(out + dbase + 16) = df[1];
    }
    if (t == T_STEPS - 1) {
      const size_t fbase = OUT_HFINAL + (size_t)(brow0 + l15) * DR2 + colb;
      *(f32x4*)(out + fbase)      = hn[0];
      *(f32x4*)(out + fbase + 16) = hn[1];
    }
    zraw = znext;
  }
}

extern "C" void kernel_launch(void* const* d_in, const int* in_sizes, int n_in,
                              void* d_out, int out_size, void* d_ws, size_t ws_size,
                              hipStream_t stream) {
  const float* s_all   = (const float*)d_in[0];  // all_data_static [32,4096,512]
  const float* thr_all = (const float*)d_in[1];  // threshold_nc   [32,4096,1]
  const float* h0      = (const float*)d_in[2];  // all_data_dynamic_now [4096,512]
  const float* w1      = (const float*)d_in[3];  // w1 [1024,512]
  const float* p_logit = (const float*)d_in[4];
  const float* p_scale = (const float*)d_in[5];
  float* out = (float*)d_out;

  unsigned char* w1f = (unsigned char*)d_ws;     // 512 KB fragment-ordered fp8

  hipLaunchKernelGGL(quant_w1, dim3(64), dim3(256), 0, stream, w1, w1f);
  hipLaunchKernelGGL(dense_zs, dim3(1024), dim3(1024), 0, stream, s_all, w1f, out);
  hipLaunchKernelGGL(evolve_fp8, dim3(256), dim3(1024), 0, stream,
                     thr_all, h0, w1f, p_logit, p_scale, out);
}

// Round 11
// 257.728 us; speedup vs baseline: 1.2077x; 1.2077x over previous
//
#include <hip/hip_runtime.h>

typedef __attribute__((ext_vector_type(4))) float f32x4;

#define T_STEPS 32
#define T_LDS   16              /* steps whose z_s residual stays in LDS */
#define NROWS 4096
#define DR2 512
#define EXP_HALF 0.6065306597126334f

#define OUT_HFINAL 67108864ul           /* 32*4096*512              */
#define OUT_DIFF   69206016ul           /* + 4096*512               */
#define SLOT_F32   2097152ul            /* 4096*512 f32 per t-slot  */

__device__ __forceinline__ unsigned char f2fp8(float f) {
  return (unsigned char)__builtin_amdgcn_cvt_pk_fp8_f32(f, f, 0, false);
}

// LDS-only barrier: skips the vmcnt(0) drain __syncthreads would emit.
__device__ __forceinline__ void barrier_lds() {
  asm volatile("s_waitcnt lgkmcnt(0)" ::: "memory");
  __builtin_amdgcn_s_barrier();
  asm volatile("" ::: "memory");
}

// z_s[t] (t>=T_LDS) stored as fp8 e4m3 residual r = z_s - 256, aliased into
// d_out (diff slot t for t<31, hfinal for t=31). Block-self-owned: written in
// phase 1 by block eb, read by the SAME block at phase-2 step t, overwritten
// by the same block's diff[t] at step t+1 -- pure program order, no races.
__device__ __forceinline__ float* zs_slot(float* out, int t) {
  return out + (t < 31 ? OUT_DIFF + (size_t)t * SLOT_F32 : OUT_HFINAL);
}
__device__ __forceinline__ unsigned char* zs_blk8(float* out, int t, int eb) {
  return (unsigned char*)zs_slot(out, t) + (size_t)eb * 32768;
}

// A_lds fragment layout with XOR swizzle:
//   cell (row r, k-col c):  byte = (c>>5)*512 + ((c>>3)&3)*128
//                                + ((r ^ ((c>>3)&15)) & 15)*8 + (c&7)

// ---------- prologue: w1 [1024][512] f32 -> w1f fragment-ordered fp8
__global__ __launch_bounds__(256) void quant_w1(const float* __restrict__ w1,
                                                unsigned char* __restrict__ w1f) {
  const int half = blockIdx.x >> 5;       // 0..1
  const int ct   = blockIdx.x & 31;       // 0..31
  const int l15  = threadIdx.x & 15;
  const int kk   = threadIdx.x >> 4;      // 0..15
  const int col  = ct * 16 + l15;
  const int K0   = half * 512;
#pragma unroll
  for (int lg = 0; lg < 4; lg++) {
    unsigned long long v = 0;
#pragma unroll
    for (int e = 0; e < 8; e++) {
      int k = K0 + kk * 32 + lg * 8 + e;
      unsigned long long b = f2fp8(w1[(size_t)k * 512 + col]);
      v |= b << (8 * e);
    }
    *(unsigned long long*)(w1f + (size_t)half * 262144 + ct * 8192 + kk * 512
                           + lg * 128 + l15 * 8) = v;
  }
}

// ---------- fused kernel: 256 blocks x 1024 threads, 16 rows/block.
// Phase 1: z_s[t] = s_t[own rows] @ W1s for all t (W1s frags in regs);
//          t < T_LDS -> residual kept in LDS; t >= T_LDS -> aliased d_out.
// Phase 2: recurrence (W1h frags in the SAME registers).
__global__ __attribute__((amdgpu_flat_work_group_size(1024, 1024),
                          amdgpu_waves_per_eu(4, 4)))
void evolve_fused(
    const float* __restrict__ s_all,        // [32][4096][512] f32
    const float* __restrict__ thr_all,      // [32][4096]
    const float* __restrict__ h0,           // [4096][512]
    const unsigned char* __restrict__ w1f,  // fragment-ordered fp8
    const float* __restrict__ p_logit,
    const float* __restrict__ p_scale,
    float* __restrict__ out)
{
  __shared__ __align__(16) unsigned char zs_lds[T_LDS * 8192];   // 128 KB
  __shared__ __align__(16) unsigned char A_lds[2][8192];         // 16 KB
  __shared__ float thr_lds[T_STEPS * 16];                        // 2 KB
  __shared__ float partial[16][17];

  const int tid  = threadIdx.x;
  const int lane = tid & 63;
  const int wave = tid >> 6;              // 0..15
  const int l15  = lane & 15;
  const int lg   = lane >> 4;
  const int brow0 = blockIdx.x * 16;
  const int colbase = wave * 32 + l15;

  if (tid < T_STEPS * 16)
    thr_lds[tid] = thr_all[(size_t)(tid >> 4) * NROWS + brow0 + (tid & 15)];

  // ================= PHASE 1: z_s residuals for own rows ================
  long Bv[2][16];                         // W1s fragments (reused as W1h later)
#pragma unroll
  for (int n = 0; n < 2; n++)
#pragma unroll
    for (int kk = 0; kk < 16; kk++)
      Bv[n][kk] = *(const long*)(w1f + 262144
                   + (size_t)(wave * 2 + n) * 8192 + kk * 512 + lane * 8);

  // staging: wave stages row (brow0+wave), lane covers 8 k-cols
  const int di = (lane >> 2) * 512 + (lane & 3) * 128
               + ((wave ^ l15) & 15) * 8;          // swizzled slot (e=0)
  const float* sbase = s_all + ((size_t)brow0 + wave) * DR2 + lane * 8;

  float4 v0 = *(const float4*)sbase;
  float4 v1 = *(const float4*)(sbase + 4);
  {
    int pa = __builtin_amdgcn_cvt_pk_fp8_f32(v0.x, v0.y, 0, false);
    int pw0 = __builtin_amdgcn_cvt_pk_fp8_f32(v0.z, v0.w, pa, true);
    int pb = __builtin_amdgcn_cvt_pk_fp8_f32(v1.x, v1.y, 0, false);
    int pw1 = __builtin_amdgcn_cvt_pk_fp8_f32(v1.z, v1.w, pb, true);
    *(uint2*)(A_lds[0] + di) = make_uint2((unsigned)pw0, (unsigned)pw1);
  }
  barrier_lds();

#pragma unroll 2
  for (int t = 0; t < T_STEPS; t++) {
    if (t < T_STEPS - 1) {
      const float* p = sbase + (size_t)(t + 1) * NROWS * DR2;
      v0 = *(const float4*)p;
      v1 = *(const float4*)(p + 4);
    }
    // acc init -256: D = s@W1s - 256 = residual directly
    f32x4 acc[2];
#pragma unroll
    for (int n = 0; n < 2; n++)
#pragma unroll
      for (int i = 0; i < 4; i++) acc[n][i] = -256.0f;
    const unsigned char* buf = A_lds[t & 1];
#pragma unroll
    for (int kk = 0; kk < 16; kk++) {
      long a = *(const long*)(buf + kk * 512 + lg * 128
                              + ((l15 ^ ((kk * 4 + lg) & 15)) << 3));
      acc[0] = __builtin_amdgcn_mfma_f32_16x16x32_fp8_fp8(a, Bv[0][kk], acc[0], 0, 0, 0);
      acc[1] = __builtin_amdgcn_mfma_f32_16x16x32_fp8_fp8(a, Bv[1][kk], acc[1], 0, 0, 0);
    }
    int p0 = __builtin_amdgcn_cvt_pk_fp8_f32(acc[0][0], acc[0][1], 0, false);
    p0 = __builtin_amdgcn_cvt_pk_fp8_f32(acc[0][2], acc[0][3], p0, true);
    int p1 = __builtin_amdgcn_cvt_pk_fp8_f32(acc[1][0], acc[1][1], 0, false);
    p1 = __builtin_amdgcn_cvt_pk_fp8_f32(acc[1][2], acc[1][3], p1, true);

    // stage next s-tile BEFORE the global zs store (store stays last vmem op)
    if (t < T_STEPS - 1) {
      int pa = __builtin_amdgcn_cvt_pk_fp8_f32(v0.x, v0.y, 0, false);
      int pw0 = __builtin_amdgcn_cvt_pk_fp8_f32(v0.z, v0.w, pa, true);
      int pb = __builtin_amdgcn_cvt_pk_fp8_f32(v1.x, v1.y, 0, false);
      int pw1 = __builtin_amdgcn_cvt_pk_fp8_f32(v1.z, v1.w, pb, true);
      *(uint2*)(A_lds[(t + 1) & 1] + di) = make_uint2((unsigned)pw0, (unsigned)pw1);
    }
    if (t < T_LDS)
      *(uint2*)(zs_lds + t * 8192 + (size_t)tid * 8) =
          make_uint2((unsigned)p0, (unsigned)p1);
    else
      *(uint2*)(zs_blk8(out, t, blockIdx.x) + (size_t)tid * 8) =
          make_uint2((unsigned)p0, (unsigned)p1);
    barrier_lds();
  }

  // ================= PHASE 1.5: swap weights to W1h, load h =============
#pragma unroll
  for (int n = 0; n < 2; n++)
#pragma unroll
    for (int kk = 0; kk < 16; kk++)
      Bv[n][kk] = *(const long*)(w1f + (size_t)(wave * 2 + n) * 8192
                                 + kk * 512 + lane * 8);

  // h state in registers (MFMA C/D layout): row = lg*4+i, col = colbase+n*16
  f32x4 h[2];
#pragma unroll
  for (int n = 0; n < 2; n++)
#pragma unroll
    for (int i = 0; i < 4; i++)
      h[n][i] = h0[(size_t)(brow0 + lg * 4 + i) * DR2 + colbase + n * 16];

  const float glogit = *p_logit;
  const float gscale = *p_scale;

  uint2 zraw = make_uint2(0u, 0u), znext = make_uint2(0u, 0u);

  // ================= PHASE 2: recurrence ================================
#pragma unroll 1
  for (int t = 0; t < T_STEPS; t++) {
    // ---- stage h (fp8) into A_lds[0] (swizzled fragment layout)
#pragma unroll
    for (int n = 0; n < 2; n++) {
      int c = colbase + n * 16;
      int base = (c >> 5) * 512 + ((c >> 3) & 3) * 128 + (c & 7);
      int x = (c >> 3) & 15;
#pragma unroll
      for (int i = 0; i < 4; i++) {
        int r = lg * 4 + i;
        A_lds[0][base + ((r ^ x) & 15) * 8] = f2fp8(h[n][i]);
      }
    }
    // prefetch next HBM-resident z_s (only steps >= T_LDS need it)
    if (t + 1 >= T_LDS && t + 1 < T_STEPS)
      znext = *(const uint2*)(zs_blk8(out, t + 1, blockIdx.x) + (size_t)tid * 8);
    barrier_lds();                        // B1 (LDS-only: no vmcnt drain)

    // ---- GEMM: z = 256 + h @ W1h
    f32x4 acc[2];
#pragma unroll
    for (int n = 0; n < 2; n++)
#pragma unroll
      for (int i = 0; i < 4; i++) acc[n][i] = 256.0f;
#pragma unroll
    for (int kk = 0; kk < 16; kk++) {
      long a = *(const long*)(A_lds[0] + kk * 512 + lg * 128
                              + ((l15 ^ ((kk * 4 + lg) & 15)) << 3));
      acc[0] = __builtin_amdgcn_mfma_f32_16x16x32_fp8_fp8(a, Bv[0][kk], acc[0], 0, 0, 0);
      acc[1] = __builtin_amdgcn_mfma_f32_16x16x32_fp8_fp8(a, Bv[1][kk], acc[1], 0, 0, 0);
    }
    // ---- z += residual: LDS-resident for t < T_LDS (lgkmcnt-only consume,
    //      never ordered behind the store queue), HBM prefetch otherwise
    uint2 zr;
    if (t < T_LDS)
      zr = *(const uint2*)(zs_lds + t * 8192 + (size_t)tid * 8);
    else
      zr = zraw;
    {
      const unsigned int zw[2] = { zr.x, zr.y };
#pragma unroll
      for (int j = 0; j < 8; j++) {
        unsigned int b = (zw[j >> 2] >> ((j & 3) * 8)) & 0xffu;
        unsigned int man = (b & 0x7fu) << 20;
        unsigned int bits = ((b & 0x80u) << 24) | (man + (120u << 23));
        acc[j >> 2][j & 3] += __uint_as_float(bits);
      }
    }

    // ---- epilogue: cand, per-row |cand-h| partial sums
    f32x4 cand[2];
#pragma unroll
    for (int i = 0; i < 4; i++) {
      int r = lg * 4 + i;
      float th = thr_lds[t * 16 + r];
      float s = 0.f;
#pragma unroll
      for (int n = 0; n < 2; n++) {
        float hh = h[n][i];
        float x  = acc[n][i] * th + hh * (1.0f - th);
        float c  = EXP_HALF / (1.0f + __expf(-x));
        cand[n][i] = c;
        s += fabsf(c - hh);
      }
      s += __shfl_xor(s, 1);
      s += __shfl_xor(s, 2);
      s += __shfl_xor(s, 4);
      s += __shfl_xor(s, 8);
      if (l15 == 0) partial[r][wave] = s;
    }
    barrier_lds();                        // B2 (LDS-only)

    // ---- gate: all lanes redundantly reduce 16 wave-partials
    float tot = partial[l15][lg] + partial[l15][lg + 4]
              + partial[l15][lg + 8] + partial[l15][lg + 12];
    tot += __shfl_xor(tot, 16);
    tot += __shfl_xor(tot, 32);           // lane holds total for row l15
    float gme = 1.0f / (1.0f + __expf(-(glogit + gscale * (tot * (1.0f / 512.0f)))));

    // ---- gated update, write states[t], diff[t-1]
    const size_t srowbase = (size_t)t * NROWS + brow0;
#pragma unroll
    for (int i = 0; i < 4; i++) {
      int r = lg * 4 + i;
      float g = __shfl(gme, r);           // row r's gate lives at lane r
#pragma unroll
      for (int n = 0; n < 2; n++) {
        int c = colbase + n * 16;
        float hh = h[n][i];
        float hn = g * hh + (1.0f - g) * cand[n][i];
        h[n][i] = hn;
        out[(srowbase + r) * DR2 + c] = hn;
        if (t > 0) out[OUT_DIFF + (srowbase - NROWS + r) * DR2 + c] = hn - hh;
      }
    }
    if (t == T_STEPS - 1) {
#pragma unroll
      for (int i = 0; i < 4; i++) {
        int r = lg * 4 + i;
#pragma unroll
        for (int n = 0; n < 2; n++)
          out[OUT_HFINAL + (size_t)(brow0 + r) * DR2 + colbase + n * 16] = h[n][i];
      }
    }
    zraw = znext;
  }
}

extern "C" void kernel_launch(void* const* d_in, const int* in_sizes, int n_in,
                              void* d_out, int out_size, void* d_ws, size_t ws_size,
                              hipStream_t stream) {
  const float* s_all   = (const float*)d_in[0];  // all_data_static [32,4096,512]
  const float* thr_all = (const float*)d_in[1];  // threshold_nc   [32,4096,1]
  const float* h0      = (const float*)d_in[2];  // all_data_dynamic_now [4096,512]
  const float* w1      = (const float*)d_in[3];  // w1 [1024,512]
  const float* p_logit = (const float*)d_in[4];
  const float* p_scale = (const float*)d_in[5];
  float* out = (float*)d_out;

  unsigned char* w1f = (unsigned char*)d_ws;     // 512 KB fragment-ordered fp8

  hipLaunchKernelGGL(quant_w1, dim3(64), dim3(256), 0, stream, w1, w1f);
  hipLaunchKernelGGL(evolve_fused, dim3(256), dim3(1024), 0, stream,
                     s_all, thr_all, h0, w1f, p_logit, p_scale, out);
}